// Round 5
// baseline (3503.611 us; speedup 1.0000x reference)
//
#include <hip/hip_runtime.h>
#include <math.h>

#define NB 8
#define NN 2048
#define NM 2048
#define NITERS 50

static constexpr float F_EPS  = 0.005f;
static constexpr float LOG2E  = 1.4426950408889634f;
static constexpr float KK     = LOG2E / F_EPS;      // 288.539...
static constexpr float TWOK   = 2.0f * KK;
static constexpr float NEG_LOG2N = -11.0f;          // -log2(2048)

__device__ __forceinline__ float fexp2(float x) { return __builtin_amdgcn_exp2f(x); }
__device__ __forceinline__ float flog2(float x) { return __builtin_amdgcn_logf(x); }

struct SmemT {
    float2 part [32][65];   // [row][lane] padded
    float2 part2[32][9];    // [row][seg]
    float  wsum[4];
};

// Per-batch barrier: 64 wgs arrive (monotone counter), spin on agent-scope
// acquire load. Release on the add orders prior global writes (cross-XCD safe).
__device__ __forceinline__ void batch_barrier(int* cnt, int phase)
{
    __syncthreads();
    if (threadIdx.x == 0) {
        __hip_atomic_fetch_add(cnt, 1, __ATOMIC_RELEASE, __HIP_MEMORY_SCOPE_AGENT);
        const int target = 64 * phase;
        while (__hip_atomic_load(cnt, __ATOMIC_ACQUIRE, __HIP_MEMORY_SCOPE_AGENT) < target)
            __builtin_amdgcn_s_sleep(1);
    }
    __syncthreads();
}

// One half-sweep for this wg's 32 rows (4 waves x 8 rows), m = 0..2047.
// Identical math to the verified R4 sink_update (absmax 0.0).
__device__ __forceinline__ void half_sweep(
    const float4* __restrict__ Pin_b,    // packed opposite side, + b*NM
    const float*  __restrict__ Vrow,     // raw points + (b*NN+rowbase)*3
    float4*       __restrict__ Pout_row, // packed out + b*NN + rowbase
    SmemT& sm)
{
    const int tid  = threadIdx.x;
    const int lane = tid & 63;
    const int wave = tid >> 6;

    float xs0[8], xs1[8], xs2[8];
    {
        const float* vb = Vrow + (size_t)(wave * 8) * 3;
        #pragma unroll
        for (int r = 0; r < 8; ++r) {
            xs0[r] = TWOK * vb[r*3+0];
            xs1[r] = TWOK * vb[r*3+1];
            xs2[r] = TWOK * vb[r*3+2];
        }
    }

    const float4* __restrict__ pp = Pin_b + lane;

    float rm[8], rs[8];
    #pragma unroll
    for (int r = 0; r < 8; ++r) { rm[r] = -1e30f; rs[r] = 0.f; }

    for (int ib = 0; ib < 8; ++ib) {
        const float4 p0 = pp[(ib*4 + 0) * 64];
        const float4 p1 = pp[(ib*4 + 1) * 64];
        const float4 p2 = pp[(ib*4 + 2) * 64];
        const float4 p3 = pp[(ib*4 + 3) * 64];
        #pragma unroll
        for (int r = 0; r < 8; ++r) {
            const float z0 = fmaf(xs0[r], p0.x, fmaf(xs1[r], p0.y, fmaf(xs2[r], p0.z, p0.w)));
            const float z1 = fmaf(xs0[r], p1.x, fmaf(xs1[r], p1.y, fmaf(xs2[r], p1.z, p1.w)));
            const float z2 = fmaf(xs0[r], p2.x, fmaf(xs1[r], p2.y, fmaf(xs2[r], p2.z, p2.w)));
            const float z3 = fmaf(xs0[r], p3.x, fmaf(xs1[r], p3.y, fmaf(xs2[r], p3.z, p3.w)));
            const float cm = fmaxf(fmaxf(z0, z1), fmaxf(z2, z3));
            const float nm = fmaxf(rm[r], cm);
            const float s  = (fexp2(z0 - nm) + fexp2(z1 - nm))
                           + (fexp2(z2 - nm) + fexp2(z3 - nm));
            rs[r] = fmaf(rs[r], fexp2(rm[r] - nm), s);
            rm[r] = nm;
        }
    }

    #pragma unroll
    for (int r = 0; r < 8; ++r) sm.part[wave*8 + r][lane] = make_float2(rm[r], rs[r]);
    __syncthreads();

    {   // stage 2: 256 threads fold 8 lane-partials each
        const int row = tid >> 3, seg = tid & 7;
        float m8 = -1e30f;
        float2 v[8];
        #pragma unroll
        for (int k = 0; k < 8; ++k) { v[k] = sm.part[row][seg*8 + k]; m8 = fmaxf(m8, v[k].x); }
        float s8 = 0.f;
        #pragma unroll
        for (int k = 0; k < 8; ++k) s8 = fmaf(v[k].y, fexp2(v[k].x - m8), s8);
        sm.part2[row][seg] = make_float2(m8, s8);
    }
    __syncthreads();

    if (tid < 32) {   // stage 3: final fold + packed write
        float gm = -1e30f;
        float2 v[8];
        #pragma unroll
        for (int k = 0; k < 8; ++k) { v[k] = sm.part2[tid][k]; gm = fmaxf(gm, v[k].x); }
        float s = 0.f;
        #pragma unroll
        for (int k = 0; k < 8; ++k) s = fmaf(v[k].y, fexp2(v[k].x - gm), s);
        const float lse2 = gm + flog2(s);
        const float* vp = Vrow + (size_t)tid * 3;
        Pout_row[tid] = make_float4(vp[0], vp[1], vp[2], NEG_LOG2N - lse2);
    }
    __syncthreads();
}

// ---------------------------------------------------------------------------
// Persistent kernel: pack -> 50x (f-half, bar, g-half, bar) -> final loss.
// grid = 512 wgs x 256 thr; 2 wgs/CU co-resident (90ish VGPR, 19KB LDS).
// batch = blockIdx&7: under round-robin dispatch all 64 wgs of a batch share
// an XCD (perf only; correctness from agent-scope atomics).
// ---------------------------------------------------------------------------
__global__ __launch_bounds__(256, 2) void sinkhorn_persist(
    const float* __restrict__ X, const float* __restrict__ Y,
    float4* __restrict__ Px, float4* __restrict__ Py,
    int* __restrict__ cnt, float* __restrict__ out)
{
    __shared__ SmemT sm;
    const int tid     = threadIdx.x;
    const int b       = blockIdx.x & 7;
    const int rowbase = (blockIdx.x >> 3) * 32;
    int* mycnt = cnt + b * 16;

    const float*  Xrow = X + ((size_t)(b * NN + rowbase)) * 3;
    const float*  Yrow = Y + ((size_t)(b * NM + rowbase)) * 3;
    float4* PxRow = Px + b * NN + rowbase;
    float4* PyRow = Py + b * NM + rowbase;
    const float4* PxB = Px + b * NN;
    const float4* PyB = Py + b * NM;

    // pack my 32 rows of Py (dual g = 0)
    if (tid < 32) {
        const float* vp = Yrow + (size_t)tid * 3;
        const float v0 = vp[0], v1 = vp[1], v2 = vp[2];
        const float sq = fmaf(v0, v0, fmaf(v1, v1, v2*v2));
        PyRow[tid] = make_float4(v0, v1, v2, -KK * sq);
    }

    int phase = 1;
    batch_barrier(mycnt, phase);

    #pragma unroll 1
    for (int it = 0; it < NITERS; ++it) {
        half_sweep(PyB, Xrow, PxRow, sm);   // f-update
        batch_barrier(mycnt, ++phase);
        half_sweep(PxB, Yrow, PyRow, sm);   // g-update
        batch_barrier(mycnt, ++phase);
    }

    // final loss over my 32 rows x all m
    {
        const int lane = tid & 63;
        const int wave = tid >> 6;

        float xr0[8], xr1[8], xr2[8], Af[8], xq[8];
        const float4* xb = PxRow + wave * 8;
        #pragma unroll
        for (int r = 0; r < 8; ++r) {
            const float4 xp = xb[r];
            xr0[r] = xp.x; xr1[r] = xp.y; xr2[r] = xp.z; Af[r] = xp.w;
            xq[r]  = fmaf(xp.x, xp.x, fmaf(xp.y, xp.y, xp.z * xp.z));
        }

        const float4* __restrict__ pp = PyB + lane;
        float acc = 0.f;
        for (int i = 0; i < 32; ++i) {
            const float4 p = pp[i * 64];
            const float ysq = fmaf(p.x, p.x, fmaf(p.y, p.y, p.z * p.z));
            #pragma unroll
            for (int r = 0; r < 8; ++r) {
                const float dot = fmaf(xr0[r], p.x, fmaf(xr1[r], p.y, xr2[r] * p.z));
                const float cc  = fmaxf(fmaf(-2.f, dot, xq[r] + ysq), 0.f);
                const float zp  = fmaf(TWOK, dot, Af[r] + p.w);
                acc = fmaf(fexp2(zp), cc, acc);
            }
        }
        #pragma unroll
        for (int o = 32; o > 0; o >>= 1) acc += __shfl_xor(acc, o);
        if (lane == 0) sm.wsum[wave] = acc;
        __syncthreads();
        if (tid == 0) {
            atomicAdd(out, (sm.wsum[0] + sm.wsum[1] + sm.wsum[2] + sm.wsum[3]) * (1.0f / NB));
        }
    }
}

// ---------------------------------------------------------------------------
extern "C" void kernel_launch(void* const* d_in, const int* in_sizes, int n_in,
                              void* d_out, int out_size, void* d_ws, size_t ws_size,
                              hipStream_t stream)
{
    const float* x = (const float*)d_in[0];
    const float* y = (const float*)d_in[1];
    float4* Px = (float4*)d_ws;                       // [B][N] packed x-side
    float4* Py = Px + NB * NN;                        // [B][M] packed y-side
    int*    cnt = (int*)((char*)d_ws + (size_t)(NB * NN + NB * NM) * sizeof(float4));

    hipMemsetAsync(cnt, 0, NB * 16 * sizeof(int), stream);
    hipMemsetAsync(d_out, 0, sizeof(float), stream);

    sinkhorn_persist<<<NB * NN / 32, 256, 0, stream>>>(x, y, Px, Py, cnt, (float*)d_out);
}